// Round 1
// 757.752 us; speedup vs baseline: 1.2360x; 1.2360x over previous
//
#include <hip/hip_runtime.h>

// MemoryReader: S = (2*K^T Q - |k|^2)/8, P = softmax_n(S), mem = V P ; out = [mem, qv]
// B=16, CK=64, CV=512, N=HW=3136 (pad to 3200)
//
// R1: fragment-ordered operand layouts (all hot-loop global loads fully coalesced:
//     lane l reads base + 16*l), XCD-pinned block mapping (2 batches per XCD -> V
//     L2-resident), double-buffered P tile (1 barrier/iter instead of 2), and
//     XOR-swizzled Plds (2-way bank aliasing = free, no padding).

#define B_   16
#define CK_  64
#define CV_  512
#define N_   3136
#define NPAD 3200
#define TM   64      // query tile per workgroup
#define TN   128     // memory tile per iteration
#define NITER 25     // 25*128 = 3200 covers padded N
#define NBLK32 100   // NPAD/32  (fragment blocks for K/Q, 32 rows each)
#define NBLK16 200   // NPAD/16  (fragment blocks for V, 16 n each)

typedef __bf16 bf16_t;
typedef bf16_t bf16x8 __attribute__((ext_vector_type(8)));
typedef bf16_t bf16x4 __attribute__((ext_vector_type(4)));
typedef float  f32x16 __attribute__((ext_vector_type(16)));
typedef float  f32x4  __attribute__((ext_vector_type(4)));

#define SCALE_DOT 0.36067376022224085f  // 0.25 * log2(e)

// ---- prep 1: K,Q -> fragment-ordered bf16, plus a2[n] = |k_n|^2 * 0.125 * log2(e)
// Fragment layout (A/B operand of mfma_f32_32x32x16_bf16):
//   Kf[b][nblk][s][lane][8] where lane = (row%32) + 32*h holds K[nblk*32+row%32][16s+8h+j]
// (identical formula for Q with m in place of n).
__global__ __launch_bounds__(256) void prep_kq(const float* __restrict__ mk,
                                               const float* __restrict__ qk,
                                               bf16_t* __restrict__ Kf,
                                               bf16_t* __restrict__ Qf,
                                               float* __restrict__ a2) {
  int idx = blockIdx.x * 256 + threadIdx.x;       // 0 .. 16*3200-1 (grid exact)
  int b = idx / NPAD, n = idx % NPAD;
  bool valid = n < N_;
  int l32n = n & 31, nblk = n >> 5;
  float ss = 0.f;
  const float* mkp = mk + (size_t)b * CK_ * N_ + n;
  const float* qkp = qk + (size_t)b * CK_ * N_ + n;
  bf16x8* Kf8 = (bf16x8*)Kf;
  bf16x8* Qf8 = (bf16x8*)Qf;
  #pragma unroll
  for (int cc = 0; cc < 8; cc++) {                // c-chunk: c = 8*cc+j ; s = cc>>1, h = cc&1
    bf16x8 kv, qv8;
    #pragma unroll
    for (int j = 0; j < 8; j++) {
      int c = 8 * cc + j;
      float kx = valid ? mkp[(size_t)c * N_] : 0.f;
      float qx = valid ? qkp[(size_t)c * N_] : 0.f;
      ss += kx * kx;
      kv[j] = (bf16_t)kx;
      qv8[j] = (bf16_t)qx;
    }
    int s = cc >> 1, hh = cc & 1;
    size_t pos = (((size_t)b * NBLK32 + nblk) * 4 + s) * 64 + l32n + 32 * hh;
    Kf8[pos] = kv;
    Qf8[pos] = qv8;
  }
  a2[idx] = ss * 0.125f * 1.4426950408889634f;
}

// ---- prep 2: V -> fragment-ordered bf16
//   Vf[b][cblk][nblk][lane][8] where lane holds V[cblk*32 + lane%32][nblk*16 + (lane/32)*8 + j]
// Output-coalesced (store = Vf8[idx]); reads are row-gathers absorbed by L2.
__global__ __launch_bounds__(256) void prep_v(const float* __restrict__ mv,
                                              bf16_t* __restrict__ Vf) {
  int idx = blockIdx.x * 256 + threadIdx.x;       // chunk index (grid exact: 16*16*200*64)
  int lane = idx & 63;
  int t1 = idx >> 6;
  int nblk = t1 % NBLK16;
  int t2 = t1 / NBLK16;
  int cblk = t2 & 15;
  int b = t2 >> 4;
  int c = cblk * 32 + (lane & 31);
  int n = nblk * 16 + (lane >> 5) * 8;
  bf16x8 o;
  if (n < N_) {
    const float* p = mv + ((size_t)b * CV_ + c) * N_ + n;
    f32x4 v0 = *(const f32x4*)p;
    f32x4 v1 = *(const f32x4*)(p + 4);
    #pragma unroll
    for (int j = 0; j < 4; j++) { o[j] = (bf16_t)v0[j]; o[4 + j] = (bf16_t)v1[j]; }
  } else {
    #pragma unroll
    for (int j = 0; j < 8; j++) o[j] = (bf16_t)0.f;
  }
  ((bf16x8*)Vf)[idx] = o;
}

// ---- main fused kernel: one workgroup = (batch b, 64-query tile m0), 8 waves.
// S-phase: wave w computes 32x32 tile (n-slice i=w&3, m-slice g=w>>2) of the
//          [128 x 64] score tile; P=exp2 written bf16 to XOR-swizzled Plds[m][n].
// O-phase: wave w owns channels [64w, 64w+64); all global loads are coalesced
//          1KB fragment loads from Vf. Double-buffered Plds -> 1 barrier/iter.
__global__ __launch_bounds__(512) void attn_main(const bf16_t* __restrict__ Kf,
                                                 const bf16_t* __restrict__ Qf,
                                                 const float* __restrict__ a2,
                                                 const bf16_t* __restrict__ Vf,
                                                 float* __restrict__ out) {
  // XCD-pinned mapping: 784 = 8 XCDs * 98, blockIdx%8 ~ XCD; each XCD gets 2
  // whole batches (batch's Vf = 3.2MB -> L2-resident).
  const int xcd = blockIdx.x & 7;
  const int idx = blockIdx.x >> 3;          // 0..97
  const int q49 = idx / 49;                 // 0..1
  const int b   = xcd * 2 + q49;
  const int m0  = (idx - q49 * 49) * TM;

  const int tid  = threadIdx.x;
  const int w    = tid >> 6;
  const int lane = tid & 63;
  const int l32  = lane & 31;
  const int h    = lane >> 5;
  const int g    = w >> 2;   // S-phase m-slice (0..1)
  const int i    = w & 3;    // S-phase n-slice (0..3)

  // Plds[buf][m][n] row-major, 256B rows; bank swizzle: byte ^= (m&15)<<4.
  __shared__ __align__(16) bf16_t Plds[2][64][128];
  __shared__ float  Llds[8][32];
  __shared__ float  Linv[64];

  // loop-invariant Q fragments (coalesced fragment loads)
  const bf16x8* Qf8 = (const bf16x8*)Qf;
  const int mblk = (m0 >> 5) + g;
  bf16x8 qfrag[4];
  #pragma unroll
  for (int s = 0; s < 4; s++)
    qfrag[s] = Qf8[(((size_t)b * NBLK32 + mblk) * 4 + s) * 64 + lane];

  f32x16 acc[2][2];
  #pragma unroll
  for (int cb = 0; cb < 2; cb++)
    #pragma unroll
    for (int mb = 0; mb < 2; mb++)
      #pragma unroll
      for (int r = 0; r < 16; r++) acc[cb][mb][r] = 0.f;

  float Lpart = 0.f;
  const float*  a2b = a2 + (size_t)b * NPAD;
  const bf16x8* Kf8 = (const bf16x8*)Kf;
  // V fragment base for this wave: cblk = 2w (+1 for upper 32 channels = +12800 chunks)
  const bf16x8* Vf8 = (const bf16x8*)Vf + (((size_t)b * 16 + 2 * w) * NBLK16) * 64 + lane;

  const int wrow = 32 * g + l32;            // P write row (m)
  const int wswz = (wrow & 15) << 4;
  const int rswz = (l32 & 15) << 4;         // P read swizzle (rows l32 and 32+l32 share it)

  for (int iter = 0; iter < NITER; iter++) {
    const int n0 = iter * TN + 32 * i;

    // --- S: D[n',m'] = sum_c K[n0+n'][c] * Q[m0+32g+m'][c]  (coalesced K loads)
    f32x16 sacc;
    #pragma unroll
    for (int r = 0; r < 16; r++) sacc[r] = 0.f;
    const bf16x8* kp = Kf8 + (((size_t)b * NBLK32 + (iter * 4 + i)) * 4) * 64 + lane;
    #pragma unroll
    for (int s = 0; s < 4; s++) {
      bf16x8 kf = kp[s * 64];
      sacc = __builtin_amdgcn_mfma_f32_32x32x16_bf16(kf, qfrag[s], sacc, 0, 0, 0);
    }

    // --- P = exp2(dot*SCALE_DOT - a2[n]); pack bf16 -> swizzled LDS; col sums
    char* Pb = (char*)Plds[iter & 1];
    #pragma unroll
    for (int t = 0; t < 4; t++) {
      bf16x4 pk;
      #pragma unroll
      for (int q = 0; q < 4; q++) {
        int r = 8 * t + 4 * h + q;          // C/D row for reg 4t+q
        int n = n0 + r;
        float vv = sacc[4 * t + q] * SCALE_DOT - a2b[n];
        float p = (n < N_) ? __builtin_amdgcn_exp2f(vv) : 0.f;
        Lpart += p;
        pk[q] = (bf16_t)p;
      }
      int colb = 64 * i + 16 * t + 8 * h;   // byte offset within 256B row
      *(bf16x4*)(Pb + wrow * 256 + (colb ^ wswz)) = pk;
    }

    __syncthreads();  // P[buf] tile ready; prev iter's readers of P[buf^1] are done

    // --- O: acc[cb][mb] += V[64w+32cb+row][nb+k] * P[nb+k][32mb+col]
    const bf16x8* vp = Vf8 + (size_t)iter * 8 * 64;
    #pragma unroll
    for (int t = 0; t < 8; t++) {
      bf16x8 vf0 = vp[t * 64];              // cblk 2w   : 1KB coalesced
      bf16x8 vf1 = vp[t * 64 + 12800];      // cblk 2w+1 : NBLK16*64 chunks ahead
      bf16x8 pf0 = *(const bf16x8*)(Pb + l32 * 256 + ((32 * t + 16 * h) ^ rswz));
      bf16x8 pf1 = *(const bf16x8*)(Pb + (32 + l32) * 256 + ((32 * t + 16 * h) ^ rswz));
      acc[0][0] = __builtin_amdgcn_mfma_f32_32x32x16_bf16(vf0, pf0, acc[0][0], 0, 0, 0);
      acc[0][1] = __builtin_amdgcn_mfma_f32_32x32x16_bf16(vf0, pf1, acc[0][1], 0, 0, 0);
      acc[1][0] = __builtin_amdgcn_mfma_f32_32x32x16_bf16(vf1, pf0, acc[1][0], 0, 0, 0);
      acc[1][1] = __builtin_amdgcn_mfma_f32_32x32x16_bf16(vf1, pf1, acc[1][1], 0, 0, 0);
    }
    // no second barrier: next iter writes Plds[buf^1]; the single barrier per
    // iter orders read(buf)@i against write(buf)@i+2.
  }

  // --- column-sum (softmax denominator) reduction
  Lpart += __shfl_xor(Lpart, 32, 64);
  if (h == 0) Llds[w][l32] = Lpart;
  __syncthreads();
  if (tid < 64) {
    int gg = tid >> 5;
    float s = 0.f;
    #pragma unroll
    for (int ww = 0; ww < 4; ww++) s += Llds[4 * gg + ww][tid & 31];
    Linv[tid] = 1.0f / s;
  }
  __syncthreads();

  // --- epilogue: normalize + store fp32
  #pragma unroll
  for (int cb = 0; cb < 2; cb++) {
    #pragma unroll
    for (int mb = 0; mb < 2; mb++) {
      float rl = Linv[32 * mb + l32];
      #pragma unroll
      for (int reg = 0; reg < 16; reg++) {
        int r = (reg & 3) + 8 * (reg >> 2) + 4 * h;
        int c = 64 * w + 32 * cb + r;
        out[((size_t)b * CV_ + c) * N_ + m0 + 32 * mb + l32] = acc[cb][mb][reg] * rl;
      }
    }
  }
}

extern "C" void kernel_launch(void* const* d_in, const int* in_sizes, int n_in,
                              void* d_out, int out_size, void* d_ws, size_t ws_size,
                              hipStream_t stream) {
  const float* mk = (const float*)d_in[0];
  const float* qk = (const float*)d_in[1];
  const float* mv = (const float*)d_in[2];
  const float* qv = (const float*)d_in[3];
  float* out = (float*)d_out;

  // workspace layout (bytes):
  //   Kf  [16][100][4][64][8] bf16 : 6,553,600   @ 0
  //   Qf  [16][100][4][64][8] bf16 : 6,553,600   @ 6,553,600
  //   a2  [16][3200]     f32       :   204,800   @ 13,107,200
  //   Vf  [16][16][200][64][8]bf16 : 52,428,800  @ 13,312,000
  char* ws = (char*)d_ws;
  bf16_t* Kf = (bf16_t*)(ws);
  bf16_t* Qf = (bf16_t*)(ws + 6553600);
  float*  a2 = (float*)(ws + 13107200);
  bf16_t* Vf = (bf16_t*)(ws + 13312000);

  prep_kq<<<dim3((B_ * NPAD) / 256), dim3(256), 0, stream>>>(mk, qk, Kf, Qf, a2);
  prep_v<<<dim3((B_ * CV_ * NPAD / 8) / 256), dim3(256), 0, stream>>>(mv, Vf);
  attn_main<<<dim3(B_ * 49), dim3(512), 0, stream>>>(Kf, Qf, a2, Vf, out);

  // output 1: qv passthrough
  hipMemcpyAsync(out + (size_t)B_ * CV_ * N_, qv,
                 (size_t)B_ * CV_ * N_ * sizeof(float),
                 hipMemcpyDeviceToDevice, stream);
}

// Round 2
// 636.693 us; speedup vs baseline: 1.4710x; 1.1901x over previous
//
#include <hip/hip_runtime.h>

// MemoryReader: S = (2*K^T Q - |k|^2)/8, P = softmax_n(S), mem = V P ; out = [mem, qv]
// B=16, CK=64, CV=512, N=HW=3136 (pad to 3200)
//
// R2: full-iteration register prefetch (K + a2 + all 16 V frags issued at iter
//     top), raw lgkmcnt-only barrier (loads stay in flight across it), a2 folded
//     into MFMA C-init with pad poisoning (no per-element bounds check),
//     LDS-transpose prep_v (coalesced both sides), kernel qv copy.

#define B_   16
#define CK_  64
#define CV_  512
#define N_   3136
#define NPAD 3200
#define TM   64      // query tile per workgroup
#define TN   128     // memory tile per iteration
#define NITER 25     // 25*128 = 3200 covers padded N
#define NBLK32 100   // NPAD/32  (fragment blocks for K/Q)
#define NBLK16 200   // NPAD/16  (fragment blocks for V)

typedef __bf16 bf16_t;
typedef bf16_t bf16x8 __attribute__((ext_vector_type(8)));
typedef bf16_t bf16x4 __attribute__((ext_vector_type(4)));
typedef float  f32x16 __attribute__((ext_vector_type(16)));
typedef float  f32x4  __attribute__((ext_vector_type(4)));
typedef float  float4_t __attribute__((ext_vector_type(4)));

#define SCALE_DOT 0.36067376022224085f  // 0.25 * log2(e) ; p = exp2((dot - 0.5|k|^2)*SCALE_DOT)

// ---- prep 1: K,Q -> fragment-ordered bf16, plus A2S[n] = 0.5*|k_n|^2 (pad -> 3e38)
__global__ __launch_bounds__(256) void prep_kq(const float* __restrict__ mk,
                                               const float* __restrict__ qk,
                                               bf16_t* __restrict__ Kf,
                                               bf16_t* __restrict__ Qf,
                                               float* __restrict__ a2) {
  int idx = blockIdx.x * 256 + threadIdx.x;       // 0 .. 16*3200-1 (grid exact)
  int b = idx / NPAD, n = idx % NPAD;
  bool valid = n < N_;
  int l32n = n & 31, nblk = n >> 5;
  float ss = 0.f;
  const float* mkp = mk + (size_t)b * CK_ * N_ + n;
  const float* qkp = qk + (size_t)b * CK_ * N_ + n;
  bf16x8* Kf8 = (bf16x8*)Kf;
  bf16x8* Qf8 = (bf16x8*)Qf;
  #pragma unroll
  for (int cc = 0; cc < 8; cc++) {                // c-chunk: c = 8*cc+j ; s = cc>>1, h = cc&1
    bf16x8 kv, qv8;
    #pragma unroll
    for (int j = 0; j < 8; j++) {
      int c = 8 * cc + j;
      float kx = valid ? mkp[(size_t)c * N_] : 0.f;
      float qx = valid ? qkp[(size_t)c * N_] : 0.f;
      ss += kx * kx;
      kv[j] = (bf16_t)kx;
      qv8[j] = (bf16_t)qx;
    }
    int s = cc >> 1, hh = cc & 1;
    size_t pos = (((size_t)b * NBLK32 + nblk) * 4 + s) * 64 + l32n + 32 * hh;
    Kf8[pos] = kv;
    Qf8[pos] = qv8;
  }
  // pad rows poisoned: exp2((0 - 3e38)*SCALE) == 0, so no bounds check in hot loop
  a2[idx] = valid ? ss * 0.5f : 3.0e38f;
}

// ---- prep 2: V -> fragment-ordered bf16 via LDS transpose (coalesced read+write)
//   Vf[b][cblk][nblk][lane][8]: lane holds V[cblk*32 + lane%32][nblk*16 + (lane/32)*8 + j]
#define VCHUNK 512
__global__ __launch_bounds__(256) void prep_v(const float* __restrict__ mv,
                                              bf16_t* __restrict__ Vf) {
  __shared__ __align__(16) bf16_t T[32][VCHUNK];  // 32KB, XOR-swizzled rows
  int wg = blockIdx.x;                            // 16*16*7 = 1792 wgs
  int chunk = wg % 7;
  int t2 = wg / 7;
  int cblk = t2 & 15;
  int b = t2 >> 4;
  int n0 = chunk * VCHUNK;
  int tid = threadIdx.x;

  const float* base = mv + ((size_t)b * CV_ + cblk * 32) * N_;
  #pragma unroll
  for (int rep = 0; rep < 16; rep++) {            // 32 rows x 512 f32 = 4096 f32x4
    int idx = rep * 256 + tid;
    int cl = idx >> 7;                            // 0..31
    int np = (idx & 127) * 4;                     // 0..508
    int n = n0 + np;
    bf16x4 o;
    if (n < N_) {                                 // N_ % 4 == 0: no straddle
      f32x4 v = *(const f32x4*)(base + (size_t)cl * N_ + n);
      #pragma unroll
      for (int j = 0; j < 4; j++) o[j] = (bf16_t)v[j];
    } else {
      #pragma unroll
      for (int j = 0; j < 4; j++) o[j] = (bf16_t)0.f;
    }
    *(bf16x4*)((char*)T + cl * (VCHUNK * 2) + ((np * 2) ^ ((cl & 7) << 4))) = o;
  }
  __syncthreads();

  bf16x8* Vf8 = (bf16x8*)Vf;
  size_t outbase = (((size_t)b * 16 + cblk) * NBLK16 + (n0 >> 4)) * 64;
  #pragma unroll
  for (int pass = 0; pass < 8; pass++) {          // 32 fragment chunks of 1KB
    int idx = pass * 256 + tid;
    int nb = idx >> 6;                            // local nblk 0..31
    int ln = idx & 63;
    if (n0 + nb * 16 < NPAD) {
      int cl = ln & 31;
      int n_loc = nb * 16 + (ln >> 5) * 8;
      bf16x8 o = *(bf16x8*)((char*)T + cl * (VCHUNK * 2) +
                            ((n_loc * 2) ^ ((cl & 7) << 4)));
      Vf8[outbase + (size_t)nb * 64 + ln] = o;
    }
  }
}

// ---- qv passthrough copy (avoid SDMA blit path)
__global__ __launch_bounds__(256) void copy_qv(const float4_t* __restrict__ src,
                                               float4_t* __restrict__ dst) {
  size_t i = (size_t)blockIdx.x * 256 + threadIdx.x;   // grid exact: 25088 * 256
  dst[i] = src[i];
}

// ---- main fused kernel: one workgroup = (batch b, 64-query tile m0), 8 waves.
__global__ __launch_bounds__(512, 2) void attn_main(const bf16_t* __restrict__ Kf,
                                                    const bf16_t* __restrict__ Qf,
                                                    const float* __restrict__ A2S,
                                                    const bf16_t* __restrict__ Vf,
                                                    float* __restrict__ out) {
  // XCD-pinned mapping: each XCD owns 2 whole batches (batch Vf = 3.2MB L2-resident)
  const int xcd = blockIdx.x & 7;
  const int idx = blockIdx.x >> 3;          // 0..97
  const int q49 = idx / 49;                 // 0..1
  const int b   = xcd * 2 + q49;
  const int m0  = (idx - q49 * 49) * TM;

  const int tid  = threadIdx.x;
  const int w    = tid >> 6;
  const int lane = tid & 63;
  const int l32  = lane & 31;
  const int h    = lane >> 5;
  const int g    = w >> 2;   // S-phase m-slice (0..1)
  const int i    = w & 3;    // S-phase n-slice (0..3)

  __shared__ __align__(16) bf16_t Plds[2][64][128];   // byte ^= (m&15)<<4 swizzle
  __shared__ float  Llds[8][32];
  __shared__ float  Linv[64];

  const bf16x8* Qf8 = (const bf16x8*)Qf;
  const int mblk = (m0 >> 5) + g;
  bf16x8 qfrag[4];
  #pragma unroll
  for (int s = 0; s < 4; s++)
    qfrag[s] = Qf8[(((size_t)b * NBLK32 + mblk) * 4 + s) * 64 + lane];

  f32x16 acc[2][2];
  #pragma unroll
  for (int cb = 0; cb < 2; cb++)
    #pragma unroll
    for (int mb = 0; mb < 2; mb++)
      #pragma unroll
      for (int r = 0; r < 16; r++) acc[cb][mb][r] = 0.f;

  float Lpart = 0.f;
  const float*  a2b = A2S + (size_t)b * NPAD;
  const bf16x8* Kf8 = (const bf16x8*)Kf;
  const bf16x8* Vf8 = (const bf16x8*)Vf + (((size_t)b * 16 + 2 * w) * NBLK16) * 64 + lane;

  const int wrow = 32 * g + l32;            // P write row (m)
  const int wswz = (wrow & 15) << 4;
  const int rswz = (l32 & 15) << 4;

  for (int iter = 0; iter < NITER; iter++) {
    const int n0 = iter * TN + 32 * i;

    // ---- issue ALL of this iteration's global loads up front ----
    const bf16x8* kp = Kf8 + (((size_t)b * NBLK32 + (iter * 4 + i)) * 4) * 64 + lane;
    bf16x8 kf0 = kp[0], kf1 = kp[64], kf2 = kp[128], kf3 = kp[192];
    f32x4 na[4];
    #pragma unroll
    for (int t = 0; t < 4; t++)
      na[t] = *(const f32x4*)(a2b + n0 + 8 * t + 4 * h);
    const bf16x8* vp = Vf8 + (size_t)iter * 8 * 64;
    bf16x8 vf[16];
    #pragma unroll
    for (int t = 0; t < 8; t++) {
      vf[2 * t]     = vp[t * 64];                       // cblk 2w
      vf[2 * t + 1] = vp[t * 64 + NBLK16 * 64];         // cblk 2w+1
    }

    // ---- S: D[n'][m'] = sum_c K*Q, C-init = -0.5|k|^2 (a2 folded in) ----
    f32x16 sacc;
    #pragma unroll
    for (int t = 0; t < 4; t++)
      #pragma unroll
      for (int q = 0; q < 4; q++) sacc[4 * t + q] = -na[t][q];
    sacc = __builtin_amdgcn_mfma_f32_32x32x16_bf16(kf0, qfrag[0], sacc, 0, 0, 0);
    sacc = __builtin_amdgcn_mfma_f32_32x32x16_bf16(kf1, qfrag[1], sacc, 0, 0, 0);
    sacc = __builtin_amdgcn_mfma_f32_32x32x16_bf16(kf2, qfrag[2], sacc, 0, 0, 0);
    sacc = __builtin_amdgcn_mfma_f32_32x32x16_bf16(kf3, qfrag[3], sacc, 0, 0, 0);

    // ---- P = exp2(s*SCALE); pack bf16 -> swizzled LDS; column sums ----
    char* Pb = (char*)Plds[iter & 1];
    #pragma unroll
    for (int t = 0; t < 4; t++) {
      bf16x4 pk;
      #pragma unroll
      for (int q = 0; q < 4; q++) {
        float p = __builtin_amdgcn_exp2f(sacc[4 * t + q] * SCALE_DOT);
        Lpart += p;
        pk[q] = (bf16_t)p;
      }
      int colb = 64 * i + 16 * t + 8 * h;
      *(bf16x4*)(Pb + wrow * 256 + (colb ^ wswz)) = pk;
    }

    // ---- raw barrier: drain LDS only; V loads stay in flight (no vmcnt drain) ----
    asm volatile("s_waitcnt lgkmcnt(0)" ::: "memory");
    __builtin_amdgcn_s_barrier();

    // ---- O: acc[cb][mb] += V[.][k] * P[k][.] from prefetched regs + LDS ----
    #pragma unroll
    for (int t = 0; t < 8; t++) {
      bf16x8 pf0 = *(const bf16x8*)(Pb + l32 * 256 + ((32 * t + 16 * h) ^ rswz));
      bf16x8 pf1 = *(const bf16x8*)(Pb + (32 + l32) * 256 + ((32 * t + 16 * h) ^ rswz));
      acc[0][0] = __builtin_amdgcn_mfma_f32_32x32x16_bf16(vf[2 * t],     pf0, acc[0][0], 0, 0, 0);
      acc[0][1] = __builtin_amdgcn_mfma_f32_32x32x16_bf16(vf[2 * t],     pf1, acc[0][1], 0, 0, 0);
      acc[1][0] = __builtin_amdgcn_mfma_f32_32x32x16_bf16(vf[2 * t + 1], pf0, acc[1][0], 0, 0, 0);
      acc[1][1] = __builtin_amdgcn_mfma_f32_32x32x16_bf16(vf[2 * t + 1], pf1, acc[1][1], 0, 0, 0);
    }
    // double buffer: next iter writes Plds[buf^1]; this barrier orders
    // read(buf)@i against write(buf)@i+2.
  }

  // ---- column-sum (softmax denominator) reduction ----
  Lpart += __shfl_xor(Lpart, 32, 64);
  if (h == 0) Llds[w][l32] = Lpart;
  __syncthreads();
  if (tid < 64) {
    int gg = tid >> 5;
    float s = 0.f;
    #pragma unroll
    for (int ww = 0; ww < 4; ww++) s += Llds[4 * gg + ww][tid & 31];
    Linv[tid] = 1.0f / s;
  }
  __syncthreads();

  // ---- epilogue: normalize + store fp32 ----
  #pragma unroll
  for (int cb = 0; cb < 2; cb++) {
    #pragma unroll
    for (int mb = 0; mb < 2; mb++) {
      float rl = Linv[32 * mb + l32];
      #pragma unroll
      for (int reg = 0; reg < 16; reg++) {
        int r = (reg & 3) + 8 * (reg >> 2) + 4 * h;
        int c = 64 * w + 32 * cb + r;
        out[((size_t)b * CV_ + c) * N_ + m0 + 32 * mb + l32] = acc[cb][mb][reg] * rl;
      }
    }
  }
}

extern "C" void kernel_launch(void* const* d_in, const int* in_sizes, int n_in,
                              void* d_out, int out_size, void* d_ws, size_t ws_size,
                              hipStream_t stream) {
  const float* mk = (const float*)d_in[0];
  const float* qk = (const float*)d_in[1];
  const float* mv = (const float*)d_in[2];
  const float* qv = (const float*)d_in[3];
  float* out = (float*)d_out;

  // workspace layout (bytes):
  //   Kf  [16][100][4][64][8] bf16 : 6,553,600   @ 0
  //   Qf  [16][100][4][64][8] bf16 : 6,553,600   @ 6,553,600
  //   A2S [16][3200]     f32       :   204,800   @ 13,107,200
  //   Vf  [16][16][200][64][8]bf16 : 52,428,800  @ 13,312,000
  char* ws = (char*)d_ws;
  bf16_t* Kf = (bf16_t*)(ws);
  bf16_t* Qf = (bf16_t*)(ws + 6553600);
  float*  a2 = (float*)(ws + 13107200);
  bf16_t* Vf = (bf16_t*)(ws + 13312000);

  prep_kq<<<dim3((B_ * NPAD) / 256), dim3(256), 0, stream>>>(mk, qk, Kf, Qf, a2);
  prep_v<<<dim3(B_ * 16 * 7), dim3(256), 0, stream>>>(mv, Vf);
  attn_main<<<dim3(B_ * 49), dim3(512), 0, stream>>>(Kf, Qf, a2, Vf, out);
  copy_qv<<<dim3((B_ * CV_ * N_) / 4 / 256), dim3(256), 0, stream>>>(
      (const float4_t*)qv, (float4_t*)(out + (size_t)B_ * CV_ * N_));
}